// Round 1
// baseline (221.759 us; speedup 1.0000x reference)
//
#include <hip/hip_runtime.h>
#include <hip/hip_bf16.h>
#include <cstdint>
#include <cstddef>

// Problem constants: B=32, N=768, D=768
#define BN_ROWS 24576          // B*N
#define DD 768
#define BATCH_ELEMS (768*768)  // per-batch matrix elems

typedef __attribute__((ext_vector_type(8))) short bf16x8;
typedef __attribute__((ext_vector_type(4))) float f32x4;

static __device__ __forceinline__ unsigned short f2bf(float f) {
  unsigned int u = __builtin_bit_cast(unsigned int, f);
  unsigned int lsb = (u >> 16) & 1u;
  u += 0x7fffu + lsb;                    // round-to-nearest-even
  return (unsigned short)(u >> 16);
}

// ---------------- conversion kernels ----------------

__global__ __launch_bounds__(256) void convertX(const float* __restrict__ x,
                                                unsigned short* __restrict__ xb, int n4) {
  int idx = blockIdx.x * blockDim.x + threadIdx.x;
  int stride = gridDim.x * blockDim.x;
  for (int i = idx; i < n4; i += stride) {
    float4 v = reinterpret_cast<const float4*>(x)[i];
    ushort4 o;
    o.x = f2bf(v.x); o.y = f2bf(v.y); o.z = f2bf(v.z); o.w = f2bf(v.w);
    reinterpret_cast<ushort4*>(xb)[i] = o;
  }
}

// Transpose+convert both weights: WT[e][d] = bf16(W[d][e])
__global__ __launch_bounds__(256) void convertWT(const float* __restrict__ Wl,
                                                 const float* __restrict__ Wl1,
                                                 unsigned short* __restrict__ WlT,
                                                 unsigned short* __restrict__ Wl1T) {
  int tid = blockIdx.x * blockDim.x + threadIdx.x;
  if (tid < BATCH_ELEMS) {
    int d = tid / DD, e = tid % DD;
    WlT[e * DD + d]  = f2bf(Wl[tid]);
    Wl1T[e * DD + d] = f2bf(Wl1[tid]);
  }
}

// Per-row: rowsum (fp32), then adjnb = bf16(adj * r_inv). One block per row.
__global__ __launch_bounds__(256) void adjNorm(const float* __restrict__ adj,
                                               unsigned short* __restrict__ adjnb) {
  int row = blockIdx.x;                       // 0..B*N-1
  const float* a = adj + (size_t)row * DD;
  int t = threadIdx.x;
  float v0 = a[t], v1 = a[t + 256], v2 = a[t + 512];
  float s = v0 + v1 + v2;
  #pragma unroll
  for (int off = 32; off; off >>= 1) s += __shfl_down(s, off);
  __shared__ float wsum[4];
  int wid = t >> 6, lane = t & 63;
  if (lane == 0) wsum[wid] = s;
  __syncthreads();
  float tot = wsum[0] + wsum[1] + wsum[2] + wsum[3];
  float rinv = (tot == 0.f) ? 0.f : 1.f / tot;
  unsigned short* o = adjnb + (size_t)row * DD;
  o[t]       = f2bf(v0 * rinv);
  o[t + 256] = f2bf(v1 * rinv);
  o[t + 512] = f2bf(v2 * rinv);
}

// ---------------- GEMM core (m97-style 128x128 tile, BK=64) ----------------
// A: [Mtile=128 rows][K] row-major bf16 ; B given as B^T: [Ntile=128 rows][K] row-major bf16.
// LDS tiles 128x64 bf16, 16B-slot XOR swizzle (slot ^= row&7) applied by
// pre-swizzling the per-lane GLOBAL source address (global_load_lds dest is linear).

__device__ __forceinline__ void stage_tile(const unsigned short* __restrict__ gsrc, int ld,
                                           char* lds_base, int wchunk, int lane, int k0) {
  #pragma unroll
  for (int i = 0; i < 4; ++i) {
    int chunk = wchunk + i;                 // 0..15 -> 1KB each
    int row = chunk * 8 + (lane >> 3);      // 0..127
    int slot = (lane & 7) ^ (row & 7);      // pre-swizzled source slot
    const unsigned short* src = gsrc + (size_t)row * ld + k0 + slot * 8;
    __builtin_amdgcn_global_load_lds(
        (const __attribute__((address_space(1))) void*)src,
        (__attribute__((address_space(3))) void*)(lds_base + chunk * 1024),
        16, 0, 0);
  }
}

__device__ __forceinline__ bf16x8 frag_read(const char* lds, int rowbase, int lane, int kk) {
  int row = rowbase + (lane & 15);
  int slot = (kk * 4 + (lane >> 4)) ^ (row & 7);
  return *reinterpret_cast<const bf16x8*>(lds + row * 128 + slot * 16);
}

__device__ __forceinline__ void gemm_accum(const unsigned short* __restrict__ Ag,
                                           const unsigned short* __restrict__ Bg,
                                           int lda, int ldb, int K,
                                           char* As, char* Bs,
                                           f32x4 acc[4][4], int wid, int lane, int wr, int wc) {
  int wchunk = wid * 4;
  for (int k0 = 0; k0 < K; k0 += 64) {
    stage_tile(Ag, lda, As, wchunk, lane, k0);
    stage_tile(Bg, ldb, Bs, wchunk, lane, k0);
    __syncthreads();                       // staging complete (compiler drains vmcnt)
    #pragma unroll
    for (int kk = 0; kk < 2; ++kk) {
      bf16x8 af[4], bfr[4];
      #pragma unroll
      for (int mi = 0; mi < 4; ++mi) af[mi] = frag_read(As, wr * 64 + mi * 16, lane, kk);
      #pragma unroll
      for (int ni = 0; ni < 4; ++ni) bfr[ni] = frag_read(Bs, wc * 64 + ni * 16, lane, kk);
      #pragma unroll
      for (int mi = 0; mi < 4; ++mi)
        #pragma unroll
        for (int ni = 0; ni < 4; ++ni)
          acc[mi][ni] = __builtin_amdgcn_mfma_f32_16x16x32_bf16(af[mi], bfr[ni], acc[mi][ni], 0, 0, 0);
    }
    __syncthreads();                       // compute done before next-tile staging
  }
}

// GEMM1: e1 = Xb @ W_l1 ; output stored TRANSPOSED per batch: e1T[b][d][m] (bf16)
__global__ __launch_bounds__(256) void gemm_e1(const unsigned short* __restrict__ Xb,
                                               const unsigned short* __restrict__ W1T,
                                               unsigned short* __restrict__ e1T) {
  __shared__ char smem[32768];
  int bidx = blockIdx.x;                  // mt*6 + nt, mt in 0..191
  int mt = bidx / 6, nt = bidx % 6;
  int tid = threadIdx.x, lane = tid & 63, wid = tid >> 6;
  int wr = wid >> 1, wc = wid & 1;
  f32x4 acc[4][4] = {};
  const unsigned short* Ag = Xb + (size_t)mt * 128 * DD;
  const unsigned short* Bg = W1T + (size_t)nt * 128 * DD;
  gemm_accum(Ag, Bg, DD, DD, DD, smem, smem + 16384, acc, wid, lane, wr, wc);

  int gm0 = mt * 128;
  int b = gm0 / DD;
  int m0 = (gm0 % DD) + wr * 64 + (lane >> 4) * 4;
  unsigned short* outb = e1T + (size_t)b * BATCH_ELEMS;
  #pragma unroll
  for (int mi = 0; mi < 4; ++mi) {
    #pragma unroll
    for (int ni = 0; ni < 4; ++ni) {
      int m = m0 + mi * 16;                       // 4 consecutive rows m..m+3
      int n = nt * 128 + wc * 64 + ni * 16 + (lane & 15);  // global col (d)
      f32x4 v = acc[mi][ni];
      ushort4 o;
      o.x = f2bf(v[0]); o.y = f2bf(v[1]); o.z = f2bf(v[2]); o.w = f2bf(v[3]);
      *reinterpret_cast<ushort4*>(outb + (size_t)n * DD + m) = o;  // e1T[d][m..m+3]
    }
  }
}

// GEMM2: out = leaky_relu( adj_n[b] @ e1[b]  +  X[b] @ W_l )   (fp32 out)
__global__ __launch_bounds__(256) void gemm_out(const unsigned short* __restrict__ adjnb,
                                                const unsigned short* __restrict__ e1T,
                                                const unsigned short* __restrict__ Xb,
                                                const unsigned short* __restrict__ WlT,
                                                float* __restrict__ out) {
  __shared__ char smem[32768];
  int bidx = blockIdx.x;                  // b*36 + mt*6 + nt
  int b = bidx / 36, r = bidx % 36;
  int mt = r / 6, nt = r % 6;
  int tid = threadIdx.x, lane = tid & 63, wid = tid >> 6;
  int wr = wid >> 1, wc = wid & 1;
  f32x4 acc[4][4] = {};
  size_t bo = (size_t)b * BATCH_ELEMS;
  // aggregate branch: A = normalized adj rows (n), B^T = e1T rows (d), K = m
  gemm_accum(adjnb + bo + (size_t)mt * 128 * DD, e1T + bo + (size_t)nt * 128 * DD,
             DD, DD, DD, smem, smem + 16384, acc, wid, lane, wr, wc);
  // self branch: A = X rows (n), B^T = W_l^T rows (e), K = d
  gemm_accum(Xb + bo + (size_t)mt * 128 * DD, WlT + (size_t)nt * 128 * DD,
             DD, DD, DD, smem, smem + 16384, acc, wid, lane, wr, wc);

  float* outp = out + bo;
  int m0 = mt * 128 + wr * 64 + (lane >> 4) * 4;
  int n0 = nt * 128 + wc * 64 + (lane & 15);
  #pragma unroll
  for (int mi = 0; mi < 4; ++mi) {
    #pragma unroll
    for (int ni = 0; ni < 4; ++ni) {
      int m = m0 + mi * 16;
      int n = n0 + ni * 16;
      f32x4 v = acc[mi][ni];
      #pragma unroll
      for (int rg = 0; rg < 4; ++rg) {
        float x = v[rg];
        outp[(size_t)(m + rg) * DD + n] = x > 0.f ? x : 0.01f * x;
      }
    }
  }
}

// ---------------- launch ----------------

extern "C" void kernel_launch(void* const* d_in, const int* in_sizes, int n_in,
                              void* d_out, int out_size, void* d_ws, size_t ws_size,
                              hipStream_t stream) {
  const float* X   = (const float*)d_in[0];
  const float* adj = (const float*)d_in[1];
  const float* Wl  = (const float*)d_in[2];
  const float* Wl1 = (const float*)d_in[3];
  float* out = (float*)d_out;

  char* ws = (char*)d_ws;
  const size_t SZ_BNxD_BF16 = (size_t)BN_ROWS * DD * 2;   // 37,748,736
  unsigned short* Xb    = (unsigned short*)(ws);
  unsigned short* adjnb = (unsigned short*)(ws + SZ_BNxD_BF16);
  unsigned short* e1T   = (unsigned short*)(ws + 2 * SZ_BNxD_BF16);
  unsigned short* WlT   = (unsigned short*)(ws + 3 * SZ_BNxD_BF16);
  unsigned short* Wl1T  = (unsigned short*)(ws + 3 * SZ_BNxD_BF16 + (size_t)BATCH_ELEMS * 2);

  convertX<<<4096, 256, 0, stream>>>(X, Xb, (BN_ROWS * DD) / 4);
  convertWT<<<(BATCH_ELEMS + 255) / 256, 256, 0, stream>>>(Wl, Wl1, WlT, Wl1T);
  adjNorm<<<BN_ROWS, 256, 0, stream>>>(adj, adjnb);
  gemm_e1<<<192 * 6, 256, 0, stream>>>(Xb, Wl1T, e1T);
  gemm_out<<<32 * 36, 256, 0, stream>>>(adjnb, e1T, Xb, WlT, out);
}

// Round 2
// 189.950 us; speedup vs baseline: 1.1675x; 1.1675x over previous
//
#include <hip/hip_runtime.h>
#include <hip/hip_bf16.h>
#include <cstdint>
#include <cstddef>

// Problem constants: B=32, N=768, D=768
#define BN_ROWS 24576          // B*N
#define DD 768
#define BATCH_ELEMS (768*768)  // per-batch matrix elems

typedef __attribute__((ext_vector_type(8))) short bf16x8;
typedef __attribute__((ext_vector_type(4))) float f32x4;

static __device__ __forceinline__ unsigned short f2bf(float f) {
  unsigned int u = __builtin_bit_cast(unsigned int, f);
  unsigned int lsb = (u >> 16) & 1u;
  u += 0x7fffu + lsb;                    // round-to-nearest-even
  return (unsigned short)(u >> 16);
}

// XCD-aware bijective chunked swizzle: blocks with orig%8==x (dispatched to
// XCD x) get the contiguous logical chunk [x*chunk, (x+1)*chunk).
// Requires gridDim.x % 8 == 0 (1152 = 8*144 here).
static __device__ __forceinline__ int xcd_logical(int nblocks) {
  int orig = blockIdx.x;
  int chunk = nblocks >> 3;
  return (orig & 7) * chunk + (orig >> 3);
}

// ---------------- conversion kernels ----------------

__global__ __launch_bounds__(256) void convertX(const float* __restrict__ x,
                                                unsigned short* __restrict__ xb, int n4) {
  int idx = blockIdx.x * blockDim.x + threadIdx.x;
  int stride = gridDim.x * blockDim.x;
  for (int i = idx; i < n4; i += stride) {
    float4 v = reinterpret_cast<const float4*>(x)[i];
    ushort4 o;
    o.x = f2bf(v.x); o.y = f2bf(v.y); o.z = f2bf(v.z); o.w = f2bf(v.w);
    reinterpret_cast<ushort4*>(xb)[i] = o;
  }
}

// Transpose+convert both weights: WT[e][d] = bf16(W[d][e])
__global__ __launch_bounds__(256) void convertWT(const float* __restrict__ Wl,
                                                 const float* __restrict__ Wl1,
                                                 unsigned short* __restrict__ WlT,
                                                 unsigned short* __restrict__ Wl1T) {
  int tid = blockIdx.x * blockDim.x + threadIdx.x;
  if (tid < BATCH_ELEMS) {
    int d = tid / DD, e = tid % DD;
    WlT[e * DD + d]  = f2bf(Wl[tid]);
    Wl1T[e * DD + d] = f2bf(Wl1[tid]);
  }
}

// Per-row normalize: one wave per row, float4 loads, ushort4 stores. 4 rows/block.
__global__ __launch_bounds__(256) void adjNorm(const float* __restrict__ adj,
                                               unsigned short* __restrict__ adjnb) {
  int wid = threadIdx.x >> 6, lane = threadIdx.x & 63;
  int row = blockIdx.x * 4 + wid;               // 0..B*N-1
  const float4* a = reinterpret_cast<const float4*>(adj + (size_t)row * DD);
  float4 v[3];
  float s = 0.f;
  #pragma unroll
  for (int i = 0; i < 3; ++i) {
    v[i] = a[i * 64 + lane];
    s += (v[i].x + v[i].y) + (v[i].z + v[i].w);
  }
  #pragma unroll
  for (int off = 32; off; off >>= 1) s += __shfl_down(s, off);
  s = __shfl(s, 0);
  float rinv = (s == 0.f) ? 0.f : 1.f / s;
  ushort4* o = reinterpret_cast<ushort4*>(adjnb + (size_t)row * DD);
  #pragma unroll
  for (int i = 0; i < 3; ++i) {
    ushort4 u;
    u.x = f2bf(v[i].x * rinv); u.y = f2bf(v[i].y * rinv);
    u.z = f2bf(v[i].z * rinv); u.w = f2bf(v[i].w * rinv);
    o[i * 64 + lane] = u;
  }
}

// ---------------- GEMM core (m97-style 128x128 tile, BK=64) ----------------
// A: [Mtile=128 rows][K] row-major bf16 ; B given as B^T: [Ntile=128 rows][K] row-major bf16.
// LDS tiles 128x64 bf16, 16B-slot XOR swizzle (slot ^= row&7) applied by
// pre-swizzling the per-lane GLOBAL source address (global_load_lds dest is linear).

__device__ __forceinline__ void stage_tile(const unsigned short* __restrict__ gsrc, int ld,
                                           char* lds_base, int wchunk, int lane, int k0) {
  #pragma unroll
  for (int i = 0; i < 4; ++i) {
    int chunk = wchunk + i;                 // 0..15 -> 1KB each
    int row = chunk * 8 + (lane >> 3);      // 0..127
    int slot = (lane & 7) ^ (row & 7);      // pre-swizzled source slot
    const unsigned short* src = gsrc + (size_t)row * ld + k0 + slot * 8;
    __builtin_amdgcn_global_load_lds(
        (const __attribute__((address_space(1))) void*)src,
        (__attribute__((address_space(3))) void*)(lds_base + chunk * 1024),
        16, 0, 0);
  }
}

__device__ __forceinline__ bf16x8 frag_read(const char* lds, int rowbase, int lane, int kk) {
  int row = rowbase + (lane & 15);
  int slot = (kk * 4 + (lane >> 4)) ^ (row & 7);
  return *reinterpret_cast<const bf16x8*>(lds + row * 128 + slot * 16);
}

__device__ __forceinline__ void gemm_accum(const unsigned short* __restrict__ Ag,
                                           const unsigned short* __restrict__ Bg,
                                           int lda, int ldb, int K,
                                           char* As, char* Bs,
                                           f32x4 acc[4][4], int wid, int lane, int wr, int wc) {
  int wchunk = wid * 4;
  for (int k0 = 0; k0 < K; k0 += 64) {
    stage_tile(Ag, lda, As, wchunk, lane, k0);
    stage_tile(Bg, ldb, Bs, wchunk, lane, k0);
    __syncthreads();                       // staging complete (compiler drains vmcnt)
    #pragma unroll
    for (int kk = 0; kk < 2; ++kk) {
      bf16x8 af[4], bfr[4];
      #pragma unroll
      for (int mi = 0; mi < 4; ++mi) af[mi] = frag_read(As, wr * 64 + mi * 16, lane, kk);
      #pragma unroll
      for (int ni = 0; ni < 4; ++ni) bfr[ni] = frag_read(Bs, wc * 64 + ni * 16, lane, kk);
      #pragma unroll
      for (int mi = 0; mi < 4; ++mi)
        #pragma unroll
        for (int ni = 0; ni < 4; ++ni)
          acc[mi][ni] = __builtin_amdgcn_mfma_f32_16x16x32_bf16(af[mi], bfr[ni], acc[mi][ni], 0, 0, 0);
    }
    __syncthreads();                       // compute done before next-tile staging
  }
}

// GEMM1: e1 = Xb @ W_l1 ; output stored TRANSPOSED per batch: e1T[b][d][m] (bf16)
// Block order: nt-inner (6 consecutive logical blocks share the A-panel);
// XCD-chunked so each XCD streams a contiguous range of mt panels, W1T stays L2-hot.
__global__ __launch_bounds__(256) void gemm_e1(const unsigned short* __restrict__ Xb,
                                               const unsigned short* __restrict__ W1T,
                                               unsigned short* __restrict__ e1T) {
  __shared__ char smem[32768];
  int bidx = xcd_logical(192 * 6);        // mt*6 + nt, mt in 0..191
  int mt = bidx / 6, nt = bidx % 6;
  int tid = threadIdx.x, lane = tid & 63, wid = tid >> 6;
  int wr = wid >> 1, wc = wid & 1;
  f32x4 acc[4][4] = {};
  const unsigned short* Ag = Xb + (size_t)mt * 128 * DD;
  const unsigned short* Bg = W1T + (size_t)nt * 128 * DD;
  gemm_accum(Ag, Bg, DD, DD, DD, smem, smem + 16384, acc, wid, lane, wr, wc);

  int gm0 = mt * 128;
  int b = gm0 / DD;
  int m0 = (gm0 % DD) + wr * 64 + (lane >> 4) * 4;
  unsigned short* outb = e1T + (size_t)b * BATCH_ELEMS;
  #pragma unroll
  for (int mi = 0; mi < 4; ++mi) {
    #pragma unroll
    for (int ni = 0; ni < 4; ++ni) {
      int m = m0 + mi * 16;                       // 4 consecutive rows m..m+3
      int n = nt * 128 + wc * 64 + ni * 16 + (lane & 15);  // global col (d)
      f32x4 v = acc[mi][ni];
      ushort4 o;
      o.x = f2bf(v[0]); o.y = f2bf(v[1]); o.z = f2bf(v[2]); o.w = f2bf(v[3]);
      *reinterpret_cast<ushort4*>(outb + (size_t)n * DD + m) = o;  // e1T[d][m..m+3]
    }
  }
}

// GEMM2: out = leaky_relu( adj_n[b] @ e1[b]  +  X[b] @ W_l )   (fp32 out)
// Block order: batch-major (4 batches per XCD chunk -> per-XCD working set
// ~4.7MB ~= L2), mt-inner within batch (6 consecutive blocks share B-panel).
__global__ __launch_bounds__(256) void gemm_out(const unsigned short* __restrict__ adjnb,
                                                const unsigned short* __restrict__ e1T,
                                                const unsigned short* __restrict__ Xb,
                                                const unsigned short* __restrict__ WlT,
                                                float* __restrict__ out) {
  __shared__ char smem[32768];
  int bidx = xcd_logical(32 * 36);        // b*36 + nt*6 + mt
  int b = bidx / 36, r = bidx % 36;
  int nt = r / 6, mt = r % 6;
  int tid = threadIdx.x, lane = tid & 63, wid = tid >> 6;
  int wr = wid >> 1, wc = wid & 1;
  f32x4 acc[4][4] = {};
  size_t bo = (size_t)b * BATCH_ELEMS;
  // aggregate branch: A = normalized adj rows (n), B^T = e1T rows (d), K = m
  gemm_accum(adjnb + bo + (size_t)mt * 128 * DD, e1T + bo + (size_t)nt * 128 * DD,
             DD, DD, DD, smem, smem + 16384, acc, wid, lane, wr, wc);
  // self branch: A = X rows (n), B^T = W_l^T rows (e), K = d
  gemm_accum(Xb + bo + (size_t)mt * 128 * DD, WlT + (size_t)nt * 128 * DD,
             DD, DD, DD, smem, smem + 16384, acc, wid, lane, wr, wc);

  float* outp = out + bo;
  int m0 = mt * 128 + wr * 64 + (lane >> 4) * 4;
  int n0 = nt * 128 + wc * 64 + (lane & 15);
  #pragma unroll
  for (int mi = 0; mi < 4; ++mi) {
    #pragma unroll
    for (int ni = 0; ni < 4; ++ni) {
      int m = m0 + mi * 16;
      int n = n0 + ni * 16;
      f32x4 v = acc[mi][ni];
      #pragma unroll
      for (int rg = 0; rg < 4; ++rg) {
        float x = v[rg];
        outp[(size_t)(m + rg) * DD + n] = x > 0.f ? x : 0.01f * x;
      }
    }
  }
}

// ---------------- launch ----------------

extern "C" void kernel_launch(void* const* d_in, const int* in_sizes, int n_in,
                              void* d_out, int out_size, void* d_ws, size_t ws_size,
                              hipStream_t stream) {
  const float* X   = (const float*)d_in[0];
  const float* adj = (const float*)d_in[1];
  const float* Wl  = (const float*)d_in[2];
  const float* Wl1 = (const float*)d_in[3];
  float* out = (float*)d_out;

  char* ws = (char*)d_ws;
  const size_t SZ_BNxD_BF16 = (size_t)BN_ROWS * DD * 2;   // 37,748,736
  unsigned short* Xb    = (unsigned short*)(ws);
  unsigned short* adjnb = (unsigned short*)(ws + SZ_BNxD_BF16);
  unsigned short* e1T   = (unsigned short*)(ws + 2 * SZ_BNxD_BF16);
  unsigned short* WlT   = (unsigned short*)(ws + 3 * SZ_BNxD_BF16);
  unsigned short* Wl1T  = (unsigned short*)(ws + 3 * SZ_BNxD_BF16 + (size_t)BATCH_ELEMS * 2);

  convertX<<<4096, 256, 0, stream>>>(X, Xb, (BN_ROWS * DD) / 4);
  convertWT<<<(BATCH_ELEMS + 255) / 256, 256, 0, stream>>>(Wl, Wl1, WlT, Wl1T);
  adjNorm<<<BN_ROWS / 4, 256, 0, stream>>>(adj, adjnb);
  gemm_e1<<<192 * 6, 256, 0, stream>>>(Xb, Wl1T, e1T);
  gemm_out<<<32 * 36, 256, 0, stream>>>(adjnb, e1T, Xb, WlT, out);
}

// Round 3
// 161.395 us; speedup vs baseline: 1.3740x; 1.1769x over previous
//
#include <hip/hip_runtime.h>
#include <hip/hip_bf16.h>
#include <cstdint>
#include <cstddef>

// Problem constants: B=32, N=768, D=768
#define BN_ROWS 24576
#define DD 768
#define BE (768*768)
#define BM 384
#define BN_T 192
#define BK 64

typedef __attribute__((ext_vector_type(8))) short bf16x8;
typedef __attribute__((ext_vector_type(4))) float f32x4;

static __device__ __forceinline__ unsigned short f2bf(float f) {
  unsigned int u = __builtin_bit_cast(unsigned int, f);
  unsigned int lsb = (u >> 16) & 1u;
  u += 0x7fffu + lsb;
  return (unsigned short)(u >> 16);
}

// ---------------- conversion kernels (unchanged from R2) ----------------

__global__ __launch_bounds__(256) void convertX(const float* __restrict__ x,
                                                unsigned short* __restrict__ xb, int n4) {
  int idx = blockIdx.x * blockDim.x + threadIdx.x;
  int stride = gridDim.x * blockDim.x;
  for (int i = idx; i < n4; i += stride) {
    float4 v = reinterpret_cast<const float4*>(x)[i];
    ushort4 o;
    o.x = f2bf(v.x); o.y = f2bf(v.y); o.z = f2bf(v.z); o.w = f2bf(v.w);
    reinterpret_cast<ushort4*>(xb)[i] = o;
  }
}

__global__ __launch_bounds__(256) void convertWT(const float* __restrict__ Wl,
                                                 const float* __restrict__ Wl1,
                                                 unsigned short* __restrict__ WlT,
                                                 unsigned short* __restrict__ Wl1T) {
  int tid = blockIdx.x * blockDim.x + threadIdx.x;
  if (tid < BE) {
    int d = tid / DD, e = tid % DD;
    WlT[e * DD + d]  = f2bf(Wl[tid]);
    Wl1T[e * DD + d] = f2bf(Wl1[tid]);
  }
}

__global__ __launch_bounds__(256) void adjNorm(const float* __restrict__ adj,
                                               unsigned short* __restrict__ adjnb) {
  int wid = threadIdx.x >> 6, lane = threadIdx.x & 63;
  int row = blockIdx.x * 4 + wid;
  const float4* a = reinterpret_cast<const float4*>(adj + (size_t)row * DD);
  float4 v[3];
  float s = 0.f;
  #pragma unroll
  for (int i = 0; i < 3; ++i) {
    v[i] = a[i * 64 + lane];
    s += (v[i].x + v[i].y) + (v[i].z + v[i].w);
  }
  #pragma unroll
  for (int off = 32; off; off >>= 1) s += __shfl_down(s, off);
  s = __shfl(s, 0);
  float rinv = (s == 0.f) ? 0.f : 1.f / s;
  ushort4* o = reinterpret_cast<ushort4*>(adjnb + (size_t)row * DD);
  #pragma unroll
  for (int i = 0; i < 3; ++i) {
    ushort4 u;
    u.x = f2bf(v[i].x * rinv); u.y = f2bf(v[i].y * rinv);
    u.z = f2bf(v[i].z * rinv); u.w = f2bf(v[i].w * rinv);
    o[i * 64 + lane] = u;
  }
}

// ---------------- 8-wave 384x192 4-phase pipelined GEMM ----------------
// LDS: As[2] @ {0, 49152} (384 rows x 128B), Bs[2] @ {98304, 122880} (192 rows x 128B)
// Per K-tile: 3 stage groups of 3 x global_load_lds(16B): G0=A rows 0-191,
// G1=A rows 192-383, G2=B rows 0-191. Staged 1 group/phase, vmcnt(3) per tile
// (counted, never 0 in-loop). XOR 16B-slot swizzle (slot ^= row&7), pre-swizzled
// on the global source (gload_lds dest is linear).
// MODE 0: e1 = Xb @ W1T, transposed bf16 store (NT=12)
// MODE 1: out = leaky( adjnb@e1 + Xb@Wl ), fused 24-tile K-loop, fp32 store

template<int MODE>
__global__ __launch_bounds__(512, 2) void gemm8(
    const unsigned short* __restrict__ P0,  // MODE0: Xb     MODE1: adjnb
    const unsigned short* __restrict__ P1,  // MODE0: W1T    MODE1: e1T
    const unsigned short* __restrict__ P2,  // MODE1: Xb
    const unsigned short* __restrict__ P3,  // MODE1: WlT
    void* __restrict__ outp)
{
  __shared__ char smem[147456];
  constexpr int NT = MODE ? 24 : 12;
  const int tid = threadIdx.x, lane = tid & 63;
  const int wid = tid >> 6, wr = wid >> 1, wc = wid & 1;

  // XCD-chunked logical block id (grid 256 = 8 XCD x 32)
  const int logical = (blockIdx.x & 7) * 32 + (blockIdx.x >> 3);

  const unsigned short *Ab0, *Bb0, *Ab1 = nullptr, *Bb1 = nullptr;
  int mt, nt, b;
  if (MODE == 0) {
    mt = logical >> 2; nt = logical & 3;          // mt 0..63, nt 0..3
    b = mt >> 1;
    Ab0 = P0 + (size_t)mt * BM * DD;
    Bb0 = P1 + (size_t)nt * BN_T * DD;
  } else {
    b = logical >> 3; int r = logical & 7; mt = r >> 2; nt = r & 3;
    size_t bo = (size_t)b * BE;
    Ab0 = P0 + bo + (size_t)mt * BM * DD;   // adjnb
    Bb0 = P1 + bo + (size_t)nt * BN_T * DD; // e1T
    Ab1 = P2 + bo + (size_t)mt * BM * DD;   // Xb
    Bb1 = P3 + (size_t)nt * BN_T * DD;      // WlT
  }

  // staging lane geometry (constant per lane)
  const int srow = tid >> 3;                          // 0..63
  const int sslot = (tid & 7) ^ (srow & 7);           // pre-swizzled 16B slot
  const int lane_off = srow * DD + sslot * 8;         // element offset in 64-row panel
  const int wchunk = (tid >> 6) * 1024;               // per-wave LDS chunk base

  auto stage = [&](int s, int g) {                    // K-tile s, group g (0,1=A halves, 2=B)
    int sc = s < NT ? s : 0;                          // clamp source (dummy stage keeps vmcnt uniform)
    const unsigned short* base;
    int kk;
    if (MODE == 1 && sc >= 12) { kk = sc - 12; base = (g == 2) ? Bb1 : Ab1; }
    else                       { kk = sc;      base = (g == 2) ? Bb0 : Ab0; }
    const unsigned short* p = base + (size_t)(g == 1 ? 192 : 0) * DD + kk * BK + lane_off;
    char* dst = smem + ((g == 2) ? (98304 + (s & 1) * 24576)
                                 : ((s & 1) * 49152 + g * 24576)) + wchunk;
    #pragma unroll
    for (int i = 0; i < 3; ++i) {
      __builtin_amdgcn_global_load_lds(
          (const __attribute__((address_space(1))) void*)(p + (size_t)i * 64 * DD),
          (__attribute__((address_space(3))) void*)(dst + i * 8192), 16, 0, 0);
    }
  };

  auto frag = [&](int bufbase, int rowbase, int ks) -> bf16x8 {
    int row = rowbase + (lane & 15);
    int slot = (ks * 4 + (lane >> 4)) ^ (row & 7);
    return *reinterpret_cast<const bf16x8*>(smem + bufbase + row * 128 + slot * 16);
  };

  f32x4 acc[6][6] = {};
  bf16x8 a0[3][2], a1[3][2], bb[3][2];   // bb reused for B-half0 then B-half1

  // prologue: tile0 fully + tile1 G0 -> 12 loads/wave, keep 3 in flight
  stage(0, 0); stage(0, 1); stage(0, 2); stage(1, 0);
  asm volatile("s_waitcnt vmcnt(3)" ::: "memory");
  __builtin_amdgcn_s_barrier();

  for (int t = 0; t < NT; ++t) {
    const int Ab = (t & 1) * 49152;
    const int Bb = 98304 + (t & 1) * 24576;

    // ---- phase 0: (m-half0, n-half0) ----
    #pragma unroll
    for (int i = 0; i < 3; ++i) {
      a0[i][0] = frag(Ab, wr * 96 + i * 16, 0);
      a0[i][1] = frag(Ab, wr * 96 + i * 16, 1);
      bb[i][0] = frag(Bb, wc * 96 + i * 16, 0);
      bb[i][1] = frag(Bb, wc * 96 + i * 16, 1);
    }
    stage(t + 1, 1);
    __builtin_amdgcn_s_barrier();
    __builtin_amdgcn_s_setprio(1);
    #pragma unroll
    for (int ks = 0; ks < 2; ++ks)
      #pragma unroll
      for (int mi = 0; mi < 3; ++mi)
        #pragma unroll
        for (int ni = 0; ni < 3; ++ni)
          acc[mi][ni] = __builtin_amdgcn_mfma_f32_16x16x32_bf16(a0[mi][ks], bb[ni][ks], acc[mi][ni], 0, 0, 0);
    __builtin_amdgcn_s_setprio(0);
    __builtin_amdgcn_s_barrier();

    // ---- phase 1: (m-half1, n-half0) ----
    #pragma unroll
    for (int i = 0; i < 3; ++i) {
      a1[i][0] = frag(Ab, wr * 96 + 48 + i * 16, 0);
      a1[i][1] = frag(Ab, wr * 96 + 48 + i * 16, 1);
    }
    stage(t + 1, 2);
    __builtin_amdgcn_s_barrier();
    __builtin_amdgcn_s_setprio(1);
    #pragma unroll
    for (int ks = 0; ks < 2; ++ks)
      #pragma unroll
      for (int mi = 0; mi < 3; ++mi)
        #pragma unroll
        for (int ni = 0; ni < 3; ++ni)
          acc[3 + mi][ni] = __builtin_amdgcn_mfma_f32_16x16x32_bf16(a1[mi][ks], bb[ni][ks], acc[3 + mi][ni], 0, 0, 0);
    __builtin_amdgcn_s_setprio(0);
    __builtin_amdgcn_s_barrier();

    // ---- phase 2: (m-half1, n-half1) ----
    #pragma unroll
    for (int i = 0; i < 3; ++i) {
      bb[i][0] = frag(Bb, wc * 96 + 48 + i * 16, 0);   // overwrite with B-half1
      bb[i][1] = frag(Bb, wc * 96 + 48 + i * 16, 1);
    }
    __builtin_amdgcn_s_barrier();
    __builtin_amdgcn_s_setprio(1);
    #pragma unroll
    for (int ks = 0; ks < 2; ++ks)
      #pragma unroll
      for (int mi = 0; mi < 3; ++mi)
        #pragma unroll
        for (int ni = 0; ni < 3; ++ni)
          acc[3 + mi][3 + ni] = __builtin_amdgcn_mfma_f32_16x16x32_bf16(a1[mi][ks], bb[ni][ks], acc[3 + mi][3 + ni], 0, 0, 0);
    __builtin_amdgcn_s_setprio(0);
    __builtin_amdgcn_s_barrier();

    // ---- phase 3: (m-half0, n-half1) ----  (a0 held from ph0, bb = B-half1)
    stage(t + 2, 0);                         // writes A-half0 of buf (t&1): t's A reads done by ph1
    __builtin_amdgcn_s_barrier();
    __builtin_amdgcn_s_setprio(1);
    #pragma unroll
    for (int ks = 0; ks < 2; ++ks)
      #pragma unroll
      for (int mi = 0; mi < 3; ++mi)
        #pragma unroll
        for (int ni = 0; ni < 3; ++ni)
          acc[mi][3 + ni] = __builtin_amdgcn_mfma_f32_16x16x32_bf16(a0[mi][ks], bb[ni][ks], acc[mi][3 + ni], 0, 0, 0);
    __builtin_amdgcn_s_setprio(0);
    asm volatile("s_waitcnt vmcnt(3)" ::: "memory");   // tile t+1 fully staged; t+2.G0 in flight
    __builtin_amdgcn_s_barrier();
  }

  // ---------------- epilogue ----------------
  if (MODE == 0) {
    unsigned short* ob = (unsigned short*)outp + (size_t)b * BE;
    const int mloc = (mt & 1) * BM + wr * 96 + (lane >> 4) * 4;
    #pragma unroll
    for (int mi = 0; mi < 6; ++mi)
      #pragma unroll
      for (int ni = 0; ni < 6; ++ni) {
        int m = mloc + mi * 16;
        int d = nt * BN_T + wc * 96 + ni * 16 + (lane & 15);
        f32x4 v = acc[mi][ni];
        ushort4 o;
        o.x = f2bf(v[0]); o.y = f2bf(v[1]); o.z = f2bf(v[2]); o.w = f2bf(v[3]);
        *reinterpret_cast<ushort4*>(ob + (size_t)d * DD + m) = o;  // e1T[d][m..m+3]
      }
  } else {
    float* ob = (float*)outp + (size_t)b * BE;
    const int mloc = mt * BM + wr * 96 + (lane >> 4) * 4;
    #pragma unroll
    for (int mi = 0; mi < 6; ++mi)
      #pragma unroll
      for (int ni = 0; ni < 6; ++ni) {
        int m = mloc + mi * 16;
        int n = nt * BN_T + wc * 96 + ni * 16 + (lane & 15);
        f32x4 v = acc[mi][ni];
        #pragma unroll
        for (int j = 0; j < 4; ++j) {
          float x = v[j];
          ob[(size_t)(m + j) * DD + n] = x > 0.f ? x : 0.01f * x;
        }
      }
  }
}

// ---------------- launch ----------------

extern "C" void kernel_launch(void* const* d_in, const int* in_sizes, int n_in,
                              void* d_out, int out_size, void* d_ws, size_t ws_size,
                              hipStream_t stream) {
  const float* X   = (const float*)d_in[0];
  const float* adj = (const float*)d_in[1];
  const float* Wl  = (const float*)d_in[2];
  const float* Wl1 = (const float*)d_in[3];
  float* out = (float*)d_out;

  char* ws = (char*)d_ws;
  const size_t SZ = (size_t)BN_ROWS * DD * 2;   // 37,748,736 bytes
  unsigned short* Xb    = (unsigned short*)(ws);
  unsigned short* adjnb = (unsigned short*)(ws + SZ);
  unsigned short* e1T   = (unsigned short*)(ws + 2 * SZ);
  unsigned short* WlT   = (unsigned short*)(ws + 3 * SZ);
  unsigned short* Wl1T  = (unsigned short*)(ws + 3 * SZ + (size_t)BE * 2);

  convertX<<<4096, 256, 0, stream>>>(X, Xb, (BN_ROWS * DD) / 4);
  convertWT<<<(BE + 255) / 256, 256, 0, stream>>>(Wl, Wl1, WlT, Wl1T);
  adjNorm<<<BN_ROWS / 4, 256, 0, stream>>>(adj, adjnb);
  gemm8<0><<<256, 512, 0, stream>>>(Xb, Wl1T, nullptr, nullptr, e1T);
  gemm8<1><<<256, 512, 0, stream>>>(adjnb, e1T, Xb, WlT, out);
}

// Round 4
// 154.544 us; speedup vs baseline: 1.4349x; 1.0443x over previous
//
#include <hip/hip_runtime.h>
#include <hip/hip_bf16.h>
#include <cstdint>
#include <cstddef>

// Problem constants: B=32, N=768, D=768
#define BN_ROWS 24576
#define DD 768
#define BE (768*768)
#define BM 384
#define BN_T 192
#define BK 64

typedef __attribute__((ext_vector_type(8))) short bf16x8;
typedef __attribute__((ext_vector_type(4))) float f32x4;

static __device__ __forceinline__ unsigned short f2bf(float f) {
  unsigned int u = __builtin_bit_cast(unsigned int, f);
  unsigned int lsb = (u >> 16) & 1u;
  u += 0x7fffu + lsb;
  return (unsigned short)(u >> 16);
}

// ---------------- conversion kernels ----------------

__global__ __launch_bounds__(256) void convertX(const float* __restrict__ x,
                                                unsigned short* __restrict__ xb, int n4) {
  int idx = blockIdx.x * blockDim.x + threadIdx.x;
  int stride = gridDim.x * blockDim.x;
  for (int i = idx; i < n4; i += stride) {
    float4 v = reinterpret_cast<const float4*>(x)[i];
    ushort4 o;
    o.x = f2bf(v.x); o.y = f2bf(v.y); o.z = f2bf(v.z); o.w = f2bf(v.w);
    reinterpret_cast<ushort4*>(xb)[i] = o;
  }
}

__global__ __launch_bounds__(256) void convertWT(const float* __restrict__ Wl,
                                                 const float* __restrict__ Wl1,
                                                 unsigned short* __restrict__ WlT,
                                                 unsigned short* __restrict__ Wl1T) {
  int tid = blockIdx.x * blockDim.x + threadIdx.x;
  if (tid < BE) {
    int d = tid / DD, e = tid % DD;
    WlT[e * DD + d]  = f2bf(Wl[tid]);
    Wl1T[e * DD + d] = f2bf(Wl1[tid]);
  }
}

__global__ __launch_bounds__(256) void adjNorm(const float* __restrict__ adj,
                                               unsigned short* __restrict__ adjnb) {
  int wid = threadIdx.x >> 6, lane = threadIdx.x & 63;
  int row = blockIdx.x * 4 + wid;
  const float4* a = reinterpret_cast<const float4*>(adj + (size_t)row * DD);
  float4 v[3];
  float s = 0.f;
  #pragma unroll
  for (int i = 0; i < 3; ++i) {
    v[i] = a[i * 64 + lane];
    s += (v[i].x + v[i].y) + (v[i].z + v[i].w);
  }
  #pragma unroll
  for (int off = 32; off; off >>= 1) s += __shfl_down(s, off);
  s = __shfl(s, 0);
  float rinv = (s == 0.f) ? 0.f : 1.f / s;
  ushort4* o = reinterpret_cast<ushort4*>(adjnb + (size_t)row * DD);
  #pragma unroll
  for (int i = 0; i < 3; ++i) {
    ushort4 u;
    u.x = f2bf(v[i].x * rinv); u.y = f2bf(v[i].y * rinv);
    u.z = f2bf(v[i].z * rinv); u.w = f2bf(v[i].w * rinv);
    o[i * 64 + lane] = u;
  }
}

// ---------------- 8-wave 384x192 2-phase pipelined GEMM ----------------
// LDS: As[2] @ {0, 49152} (384 rows x 128B), Bs[2] @ {98304, 122880} (192 rows x 128B).
// Per K-tile t: ph0 = {12 ds_read(ks0); stage ALL 9 gload_lds of t+1; bar;
// 36 MFMA; bar}; ph1 = {12 ds_read(ks1); bar; 36 MFMA; vmcnt(0); bar}.
// vmcnt(0) sits ~550+ cyc after issue -> covered (L2-resident working set).
// Same-parity hazard avoided: buf[(t+1)&1] writes follow its readers' drain
// (t-1's MFMA lgkm) + an intervening full barrier.
// XOR 16B-slot swizzle (slot ^= row&7), pre-swizzled on the global source.
// MODE 0: e1 = Xb @ W1T, transposed bf16 store (NT=12)
// MODE 1: out = leaky( adjnb@e1 + Xb@Wl ), fused 24-tile K-loop, fp32 store

template<int MODE>
__global__ __launch_bounds__(512, 2) void gemm8(
    const unsigned short* __restrict__ P0,  // MODE0: Xb     MODE1: adjnb
    const unsigned short* __restrict__ P1,  // MODE0: W1T    MODE1: e1T
    const unsigned short* __restrict__ P2,  // MODE1: Xb
    const unsigned short* __restrict__ P3,  // MODE1: WlT
    void* __restrict__ outp)
{
  __shared__ char smem[147456];
  constexpr int NT = MODE ? 24 : 12;
  const int tid = threadIdx.x, lane = tid & 63;
  const int wid = tid >> 6, wr = wid >> 1, wc = wid & 1;

  // XCD-chunked logical block id (grid 256 = 8 XCD x 32)
  const int logical = (blockIdx.x & 7) * 32 + (blockIdx.x >> 3);

  const unsigned short *Ab0, *Bb0, *Ab1 = nullptr, *Bb1 = nullptr;
  int mt, nt, b;
  if (MODE == 0) {
    mt = logical >> 2; nt = logical & 3;          // mt 0..63, nt 0..3
    b = mt >> 1;
    Ab0 = P0 + (size_t)mt * BM * DD;
    Bb0 = P1 + (size_t)nt * BN_T * DD;
  } else {
    b = logical >> 3; int r = logical & 7; mt = r >> 2; nt = r & 3;
    size_t bo = (size_t)b * BE;
    Ab0 = P0 + bo + (size_t)mt * BM * DD;   // adjnb
    Bb0 = P1 + bo + (size_t)nt * BN_T * DD; // e1T
    Ab1 = P2 + bo + (size_t)mt * BM * DD;   // Xb
    Bb1 = P3 + (size_t)nt * BN_T * DD;      // WlT
  }

  // staging lane geometry (constant per lane)
  const int srow = tid >> 3;                          // 0..63
  const int sslot = (tid & 7) ^ (srow & 7);           // pre-swizzled 16B slot
  const int lane_off = srow * DD + sslot * 8;
  const int wchunk = (tid >> 6) * 1024;

  auto stage = [&](int s, int g) {                    // K-tile s, group g (0,1=A halves, 2=B)
    int sc = s < NT ? s : 0;                          // clamp (dummy keeps vmcnt uniform)
    const unsigned short* base;
    int kk;
    if (MODE == 1 && sc >= 12) { kk = sc - 12; base = (g == 2) ? Bb1 : Ab1; }
    else                       { kk = sc;      base = (g == 2) ? Bb0 : Ab0; }
    const unsigned short* p = base + (size_t)(g == 1 ? 192 : 0) * DD + kk * BK + lane_off;
    char* dst = smem + ((g == 2) ? (98304 + (s & 1) * 24576)
                                 : ((s & 1) * 49152 + g * 24576)) + wchunk;
    #pragma unroll
    for (int i = 0; i < 3; ++i) {
      __builtin_amdgcn_global_load_lds(
          (const __attribute__((address_space(1))) void*)(p + (size_t)i * 64 * DD),
          (__attribute__((address_space(3))) void*)(dst + i * 8192), 16, 0, 0);
    }
  };

  auto frag = [&](int bufbase, int rowbase, int ks) -> bf16x8 {
    int row = rowbase + (lane & 15);
    int slot = (ks * 4 + (lane >> 4)) ^ (row & 7);
    return *reinterpret_cast<const bf16x8*>(smem + bufbase + row * 128 + slot * 16);
  };

  f32x4 acc[6][6] = {};
  bf16x8 af[6], bf[6];

  // prologue: tile 0 fully staged
  stage(0, 0); stage(0, 1); stage(0, 2);
  asm volatile("s_waitcnt vmcnt(0)" ::: "memory");
  __builtin_amdgcn_s_barrier();

  for (int t = 0; t < NT; ++t) {
    const int Ab = (t & 1) * 49152;
    const int Bb = 98304 + (t & 1) * 24576;

    // ---- phase 0: ks = 0 ----
    #pragma unroll
    for (int i = 0; i < 6; ++i) {
      af[i] = frag(Ab, wr * 96 + i * 16, 0);
      bf[i] = frag(Bb, wc * 96 + i * 16, 0);
    }
    stage(t + 1, 0); stage(t + 1, 1); stage(t + 1, 2);
    __builtin_amdgcn_s_barrier();
    __builtin_amdgcn_s_setprio(1);
    #pragma unroll
    for (int mi = 0; mi < 6; ++mi)
      #pragma unroll
      for (int ni = 0; ni < 6; ++ni)
        acc[mi][ni] = __builtin_amdgcn_mfma_f32_16x16x32_bf16(af[mi], bf[ni], acc[mi][ni], 0, 0, 0);
    __builtin_amdgcn_s_setprio(0);
    __builtin_amdgcn_s_barrier();

    // ---- phase 1: ks = 1 ----
    #pragma unroll
    for (int i = 0; i < 6; ++i) {
      af[i] = frag(Ab, wr * 96 + i * 16, 1);
      bf[i] = frag(Bb, wc * 96 + i * 16, 1);
    }
    __builtin_amdgcn_s_barrier();
    __builtin_amdgcn_s_setprio(1);
    #pragma unroll
    for (int mi = 0; mi < 6; ++mi)
      #pragma unroll
      for (int ni = 0; ni < 6; ++ni)
        acc[mi][ni] = __builtin_amdgcn_mfma_f32_16x16x32_bf16(af[mi], bf[ni], acc[mi][ni], 0, 0, 0);
    __builtin_amdgcn_s_setprio(0);
    asm volatile("s_waitcnt vmcnt(0)" ::: "memory");   // t+1 staged; issued ~550cyc ago
    __builtin_amdgcn_s_barrier();
  }

  // ---------------- epilogue ----------------
  if (MODE == 0) {
    unsigned short* ob = (unsigned short*)outp + (size_t)b * BE;
    const int mloc = (mt & 1) * BM + wr * 96 + (lane >> 4) * 4;
    #pragma unroll
    for (int mi = 0; mi < 6; ++mi)
      #pragma unroll
      for (int ni = 0; ni < 6; ++ni) {
        int m = mloc + mi * 16;
        int d = nt * BN_T + wc * 96 + ni * 16 + (lane & 15);
        f32x4 v = acc[mi][ni];
        ushort4 o;
        o.x = f2bf(v[0]); o.y = f2bf(v[1]); o.z = f2bf(v[2]); o.w = f2bf(v[3]);
        *reinterpret_cast<ushort4*>(ob + (size_t)d * DD + m) = o;  // e1T[d][m..m+3]
      }
  } else {
    float* ob = (float*)outp + (size_t)b * BE;
    const int mloc = mt * BM + wr * 96 + (lane >> 4) * 4;
    #pragma unroll
    for (int mi = 0; mi < 6; ++mi)
      #pragma unroll
      for (int ni = 0; ni < 6; ++ni) {
        int m = mloc + mi * 16;
        int n = nt * BN_T + wc * 96 + ni * 16 + (lane & 15);
        f32x4 v = acc[mi][ni];
        #pragma unroll
        for (int j = 0; j < 4; ++j) {
          float x = v[j];
          ob[(size_t)(m + j) * DD + n] = x > 0.f ? x : 0.01f * x;
        }
      }
  }
}

// ---------------- launch ----------------

extern "C" void kernel_launch(void* const* d_in, const int* in_sizes, int n_in,
                              void* d_out, int out_size, void* d_ws, size_t ws_size,
                              hipStream_t stream) {
  const float* X   = (const float*)d_in[0];
  const float* adj = (const float*)d_in[1];
  const float* Wl  = (const float*)d_in[2];
  const float* Wl1 = (const float*)d_in[3];
  float* out = (float*)d_out;

  char* ws = (char*)d_ws;
  const size_t SZ = (size_t)BN_ROWS * DD * 2;   // 37,748,736 bytes
  unsigned short* Xb    = (unsigned short*)(ws);
  unsigned short* adjnb = (unsigned short*)(ws + SZ);
  unsigned short* e1T   = (unsigned short*)(ws + 2 * SZ);
  unsigned short* WlT   = (unsigned short*)(ws + 3 * SZ);
  unsigned short* Wl1T  = (unsigned short*)(ws + 3 * SZ + (size_t)BE * 2);

  convertX<<<4096, 256, 0, stream>>>(X, Xb, (BN_ROWS * DD) / 4);
  convertWT<<<(BE + 255) / 256, 256, 0, stream>>>(Wl, Wl1, WlT, Wl1T);
  adjNorm<<<BN_ROWS / 4, 256, 0, stream>>>(adj, adjnb);
  gemm8<0><<<256, 512, 0, stream>>>(Xb, Wl1T, nullptr, nullptr, e1T);
  gemm8<1><<<256, 512, 0, stream>>>(adjnb, e1T, Xb, WlT, out);
}